// Round 5
// baseline (107.383 us; speedup 1.0000x reference)
//
#include <hip/hip_runtime.h>
#include <stdint.h>
#include <stddef.h>

// MMD loss, fused: gram = X·X^T (bf16 MFMA) + 5-kernel RBF epilogue + signed mean.
// N=8192 rows (4096 src + 4096 tgt), D=256.
//
// Round-5 structure: NO LDS; Xbt pre-transposed to MFMA fragment order
// (coalesced 1KB/wave fragment loads — round 4). NEW: macro-tiled tile
// enumeration for L2 residency. Round-4 evidence: bi-major enumeration made
// each XCD's B-panel sweep ~4MB/strip == its L2 size -> all B reads spilled
// to L3; 532MB @ ~7TB/s == the observed 75us, MfmaUtil 8.7%.
// Macro = 8x8 tiles (1024x1024 elems, 1MB working set << 4MiB XCD L2).
// Tiles enumerated macro-major, then XCD-chunked (260 ids/XCD).
//
// Fragment layout: elem(r,k) at (r>>4)*4096 + (k>>3)*128 + (r&15)*8 + (k&7)
// -> lane(lo,hi) fragment base byte = rowgroup*8192 + (kc*4+hi)*256 + lo*16.
//
// ws layout:
//   [0]     double total          (signed sum of kernel entries)
//   [8]     int    cnt_colsum     (ticket for colsum->bandwidth fusion)
//   [12]    int    cnt_gram       (ticket for gram->finalize fusion)
//   [16]    double colsum[256]
//   [2064]  float  coef           (-log2(e) / (16*bandwidth))
//   [4096]  float  sq[8192]       (row sq-norms of bf16-rounded rows)
//   [36864] ushort Xbt[8192*256]  (bf16, fragment-transposed)

#define N_TOT 8192
#define D_DIM 256
#define BS    4096
#define NB    64   // 128-row tiles per dim; 2080 upper-tri tiles (%8==0)

typedef float  f32x4  __attribute__((ext_vector_type(4)));
typedef short  bf16x8 __attribute__((ext_vector_type(8)));

__device__ __forceinline__ unsigned short f2bf(float f) {
  unsigned u = __float_as_uint(f);
  u += 0x7fffu + ((u >> 16) & 1u);   // RNE; inputs are finite
  return (unsigned short)(u >> 16);
}
__device__ __forceinline__ float bf2f(unsigned short s) {
  return __uint_as_float(((unsigned)s) << 16);
}

// ---------------- prep: f32 -> bf16 fragment-transposed copy + row sq-norms ----------------
__global__ void prep_kernel(const float* __restrict__ src, const float* __restrict__ tgt,
                            unsigned short* __restrict__ Xbt, float* __restrict__ sq) {
  int tid  = threadIdx.x;
  int row  = blockIdx.x * 4 + (tid >> 6);  // one wave per row
  int lane = tid & 63;
  const float* rowp = (row < BS) ? (src + (size_t)row * D_DIM)
                                 : (tgt + (size_t)(row - BS) * D_DIM);
  float4 v = reinterpret_cast<const float4*>(rowp)[lane];   // cols k..k+3, k = lane*4
  ushort4 b;
  b.x = f2bf(v.x); b.y = f2bf(v.y); b.z = f2bf(v.z); b.w = f2bf(v.w);
  int k = lane * 4;
  size_t off = ((size_t)(row >> 4)) * 4096 + (size_t)(k >> 3) * 128
             + (size_t)((row & 15) * 8) + (k & 7);          // k..k+3 stay contiguous
  *reinterpret_cast<ushort4*>(Xbt + off) = b;
  float fx = bf2f(b.x), fy = bf2f(b.y), fz = bf2f(b.z), fw = bf2f(b.w);
  float s = fx * fx + fy * fy + fz * fz + fw * fw;
  #pragma unroll
  for (int o = 32; o; o >>= 1) s += __shfl_down(s, o, 64);
  if (lane == 0) sq[row] = s;
}

// ---------------- column sums + (last block) bandwidth coefficient ----------------
__global__ void colsum_kernel(const float* __restrict__ src, const float* __restrict__ tgt,
                              double* __restrict__ colsum, const float* __restrict__ sq,
                              int* __restrict__ cnt, float* __restrict__ coef) {
  int d  = threadIdx.x;           // 256 threads = one per column
  int r0 = blockIdx.x * 32;       // 256 blocks * 32 rows
  float s = 0.f;
  #pragma unroll
  for (int r = 0; r < 32; ++r) {
    int row = r0 + r;
    const float* rowp = (row < BS) ? (src + (size_t)row * D_DIM)
                                   : (tgt + (size_t)(row - BS) * D_DIM);
    s += rowp[d];
  }
  atomicAdd(&colsum[d], (double)s);
  __threadfence();
  __shared__ int ticket;
  if (d == 0) ticket = atomicAdd(cnt, 1);
  __syncthreads();
  if (ticket != 255) return;

  // last block: compute coef (all colsum atomics globally visible; read atomically)
  int t = d, w = t >> 6, lane = t & 63;
  double s1 = 0.0;
  #pragma unroll
  for (int i = 0; i < 32; ++i) s1 += (double)sq[t + i * 256];
  double c  = atomicAdd(&colsum[t], 0.0);   // coherent cross-XCD read
  double s2 = c * c;
  #pragma unroll
  for (int o = 32; o; o >>= 1) { s1 += __shfl_down(s1, o, 64); s2 += __shfl_down(s2, o, 64); }
  __shared__ double rs[4], rs2[4];
  if (lane == 0) { rs[w] = s1; rs2[w] = s2; }
  __syncthreads();
  if (t == 0) {
    double S1 = rs[0] + rs[1] + rs[2] + rs[3];
    double S2 = rs2[0] + rs2[1] + rs2[2] + rs2[3];
    double S  = 2.0 * (double)N_TOT * S1 - 2.0 * S2;   // sum of all pairwise sq dists
    double bw = (S / ((double)N_TOT * (double)N_TOT - (double)N_TOT)) / 4.0;
    // u = exp(-l2/(16 bw)) = exp2(l2 * coef); kernels = u+u^2+u^4+u^8+u^16
    *coef = (float)(-1.4426950408889634 / (16.0 * bw));
  }
}

// ---------------- fused gram + RBF epilogue + (last block) finalize ----------------
// 2080 blocks, 4 waves, each wave one 64x64 quadrant of a 128x128 tile.
__launch_bounds__(256, 3)
__global__ void gram_kernel(const unsigned short* __restrict__ Xbt, const float* __restrict__ sq,
                            const float* __restrict__ coefp, double* __restrict__ total,
                            int* __restrict__ cnt, float* __restrict__ out) {
  int tid = threadIdx.x;
  int w = tid >> 6, lane = tid & 63;
  const int lo = lane & 15, hi = lane >> 4;
  const int wr = w >> 1, wc = w & 1;

  // XCD-contiguous swizzle (2080 % 8 == 0): XCD c gets ids [c*260, (c+1)*260)
  int orig = (int)blockIdx.x;
  int id   = (orig & 7) * (2080 / 8) + (orig >> 3);

  // macro-major decode: 8x8 macro grid of 8x8-tile macros.
  // off-diag macro (Mi<Mj): 64 tiles; diag macro: 36 tiles (upper-tri).
  int bi = 0, bj = 0;
  {
    int rem = id, Mi = 0, Mj = 0;
    for (Mi = 0; Mi < 8; ++Mi) {
      bool found = false;
      for (Mj = Mi; Mj < 8; ++Mj) {
        int cntm = (Mi == Mj) ? 36 : 64;
        if (rem < cntm) { found = true; break; }
        rem -= cntm;
      }
      if (found) break;
    }
    int ti, tj;
    if (Mi == Mj) {                    // upper-tri decode within 8x8
      ti = 0;
      while (rem >= 8 - ti) { rem -= 8 - ti; ++ti; }
      tj = ti + rem;
    } else {
      ti = rem >> 3; tj = rem & 7;
    }
    bi = Mi * 8 + ti; bj = Mj * 8 + tj;
  }

  float factor = ((bi < 32) == (bj < 32)) ? 1.f : -1.f;  // sign of the mean term
  if (bi != bj) factor *= 2.f;                            // symmetry weight

  // hoist epilogue scalars above the K-loop
  float coef = *coefp;
  float sqj[4], sqi[4][4];
  #pragma unroll
  for (int n = 0; n < 4; ++n) sqj[n] = sq[bj * 128 + wc * 64 + n * 16 + lo];
  #pragma unroll
  for (int m = 0; m < 4; ++m)
    #pragma unroll
    for (int r = 0; r < 4; ++r) sqi[m][r] = sq[bi * 128 + wr * 64 + m * 16 + hi * 4 + r];

  // fragment base (coalesced layout): rowgroup*8192 + (kc*4+hi)*256 + lo*16 bytes
  const char* pA = (const char*)Xbt + (size_t)(bi * 8 + wr * 4) * 8192 + (hi * 256 + lo * 16);
  const char* pB = (const char*)Xbt + (size_t)(bj * 8 + wc * 4) * 8192 + (hi * 256 + lo * 16);
  // m-step = +8192 B (one 16-row group); kc-step = +1024 B

  f32x4 acc[4][4];
  #pragma unroll
  for (int m = 0; m < 4; ++m)
    #pragma unroll
    for (int n = 0; n < 4; ++n) acc[m][n] = (f32x4){0.f, 0.f, 0.f, 0.f};

  bf16x8 a0[4], b0[4], a1[4], b1[4];

  auto load = [&](bf16x8* a, bf16x8* b, int kc) {
    #pragma unroll
    for (int m = 0; m < 4; ++m) a[m] = *(const bf16x8*)(pA + m * 8192 + kc * 1024);
    #pragma unroll
    for (int n = 0; n < 4; ++n) b[n] = *(const bf16x8*)(pB + n * 8192 + kc * 1024);
  };
  auto mm = [&](bf16x8* a, bf16x8* b) {
    #pragma unroll
    for (int m = 0; m < 4; ++m)
      #pragma unroll
      for (int n = 0; n < 4; ++n)
        acc[m][n] = __builtin_amdgcn_mfma_f32_16x16x32_bf16(a[m], b[n], acc[m][n], 0, 0, 0);
  };

  load(a0, b0, 0);
  #pragma unroll
  for (int kc = 0; kc < 8; ++kc) {       // D=256 -> 8 chunks of K=32
    if (kc & 1) {
      if (kc < 7) load(a0, b0, kc + 1);
      mm(a1, b1);
    } else {
      if (kc < 7) load(a1, b1, kc + 1);
      mm(a0, b0);
    }
  }

  // epilogue: d2 = max(sq_i + sq_j - 2g, 0); kernels = u+u^2+u^4+u^8+u^16, u=exp2(d2*coef)
  float psum = 0.f;
  #pragma unroll
  for (int m = 0; m < 4; ++m) {
    #pragma unroll
    for (int n = 0; n < 4; ++n) {
      #pragma unroll
      for (int r = 0; r < 4; ++r) {
        float g  = acc[m][n][r];
        float d2 = fmaxf(fmaf(-2.f, g, sqi[m][r] + sqj[n]), 0.f);
        float u  = __builtin_amdgcn_exp2f(d2 * coef);
        float u2 = u * u, u4 = u2 * u2, u8 = u4 * u4, u16 = u8 * u8;
        psum += (u + u2) + (u4 + u8) + u16;
      }
    }
  }
  #pragma unroll
  for (int o = 32; o; o >>= 1) psum += __shfl_down(psum, o, 64);
  __shared__ float wred[4];
  if (lane == 0) wred[w] = psum;
  __syncthreads();
  if (tid == 0) {
    atomicAdd(total, (double)((wred[0] + wred[1] + wred[2] + wred[3]) * factor));
    __threadfence();
    int ticket = atomicAdd(cnt, 1);
    if (ticket == 2079) {
      double t = atomicAdd(total, 0.0);   // coherent read of the full sum
      out[0] = (float)(t / ((double)BS * (double)BS));
    }
  }
}

extern "C" void kernel_launch(void* const* d_in, const int* in_sizes, int n_in,
                              void* d_out, int out_size, void* d_ws, size_t ws_size,
                              hipStream_t stream) {
  const float* src = (const float*)d_in[0];
  const float* tgt = (const float*)d_in[1];
  char* ws = (char*)d_ws;
  double* total   = (double*)(ws + 0);
  int*    cnt_cs  = (int*)(ws + 8);
  int*    cnt_gr  = (int*)(ws + 12);
  double* colsum  = (double*)(ws + 16);
  float*  coef    = (float*)(ws + 2064);
  float*  sq      = (float*)(ws + 4096);
  unsigned short* Xbt = (unsigned short*)(ws + 36864);
  float* out = (float*)d_out;

  (void)hipMemsetAsync(d_ws, 0, 4096, stream);  // zero total/tickets/colsum
  prep_kernel<<<2048, 256, 0, stream>>>(src, tgt, Xbt, sq);
  colsum_kernel<<<256, 256, 0, stream>>>(src, tgt, colsum, sq, cnt_cs, coef);
  gram_kernel<<<2080, 256, 0, stream>>>(Xbt, sq, coef, total, cnt_gr, out);
}